// Round 1
// baseline (489.838 us; speedup 1.0000x reference)
//
#include <hip/hip_runtime.h>

// Problem dims (fixed by setup_inputs):
//   B=2, b=16, t_q=64, t_k=128, d=512 (qs=ks=nu), slices = B*b = 32
// d_out = context [32][64][512] (f32)  ++  scores_normalized [32][64][128] (f32)
// d_ws  = pqT [32][512][64] (4MB) ++ pkT [32][512][128] (8MB), both pre-scaled by 2*log2(e)

#define DEV_INLINE __device__ __forceinline__

constexpr float C2    = 2.8853900817779268f;  // 2*log2(e): exp2(C2*x) = e^{2x}
constexpr float LOG2E = 1.4426950408889634f;

// ---------------------------------------------------------------------------
// Projection: Y[slice][n][TK] = C2 * dot(X[row], W[n])   (output transposed)
// X: [2][16*TK][512] row-major, W: [2][512][512] (out,in) row-major.
// W reads are block-uniform -> scalar loads; X streamed float4 per thread.
// ---------------------------------------------------------------------------
template<int TK>
__global__ __launch_bounds__(256)
void proj_kernel(const float* __restrict__ X, const float* __restrict__ W,
                 float* __restrict__ Y)
{
    constexpr int NT = 32;                      // n-columns per block
    const int Bidx = blockIdx.z;
    const int gm   = blockIdx.x * 256 + threadIdx.x;   // row within B-slice
    const int n0   = blockIdx.y * NT;
    const float* __restrict__ Xr = X + ((size_t)Bidx * 16 * TK + gm) * 512;
    const float* __restrict__ Wr = W + (size_t)Bidx * 512 * 512 + (size_t)n0 * 512;

    float acc[NT];
#pragma unroll
    for (int j = 0; j < NT; ++j) acc[j] = 0.f;

#pragma unroll 2
    for (int k = 0; k < 512; k += 4) {
        const float4 a = *reinterpret_cast<const float4*>(Xr + k);
#pragma unroll
        for (int j = 0; j < NT; ++j) {
            const float* wr = Wr + (size_t)j * 512 + k;   // uniform -> s_load
            acc[j] = fmaf(a.x, wr[0], acc[j]);
            acc[j] = fmaf(a.y, wr[1], acc[j]);
            acc[j] = fmaf(a.z, wr[2], acc[j]);
            acc[j] = fmaf(a.w, wr[3], acc[j]);
        }
    }

    const int bb = gm / TK, t = gm % TK;        // TK is 64/128 -> shifts
    float* __restrict__ Yp = Y + (((size_t)Bidx * 16 + bb) * 512) * TK + t;
#pragma unroll
    for (int j = 0; j < NT; ++j)
        Yp[(size_t)(n0 + j) * TK] = acc[j] * C2;   // coalesced (t contiguous over lanes)
}

// ---------------------------------------------------------------------------
// Fused score + softmax.
// score[q][k] = sum_n v_n * tanh(pq[q][n]+pk[k][n])
//             = sum_v + sum_n (-2 v_n) * rcp(1 + exp2(pqs+pks))   [pqs,pks pre-scaled]
// Block: one (slice, q-tile of 4). 512 threads: k = tid&127, nh = tid>>7 (n-quarter).
// ---------------------------------------------------------------------------
DEV_INLINE float wave_rmax(float v) {
#pragma unroll
    for (int off = 32; off; off >>= 1) v = fmaxf(v, __shfl_xor(v, off, 64));
    return v;
}
DEV_INLINE float wave_rsum(float v) {
#pragma unroll
    for (int off = 32; off; off >>= 1) v += __shfl_xor(v, off, 64);
    return v;
}

__global__ __launch_bounds__(512)
void score_softmax_kernel(const float* __restrict__ pqT,   // [32][512][64]
                          const float* __restrict__ pkT,   // [32][512][128]
                          const float* __restrict__ vatt,  // [512]
                          float* __restrict__ sc_out)      // [32][64][128]
{
    const int slice = blockIdx.x >> 4;
    const int q0    = (blockIdx.x & 15) * 4;
    const int tid   = threadIdx.x;
    const int k     = tid & 127;
    const int nh    = tid >> 7;   // 0..3

    __shared__ __align__(16) float pql[512][4];   // pql[n][j]
    __shared__ float wl[512];                     // -2*v
    __shared__ float partial[3][4][128];
    __shared__ float sc[4][128];
    __shared__ float wredm[8], wreds[8], wsum[8];

    // stage pq tile (transposed layout makes this a single float4 per thread),
    // w = -2*v, and block-reduce sum_v
    {
        const float vv = vatt[tid];
        wl[tid] = -2.f * vv;
        const float4 q4 = *reinterpret_cast<const float4*>(
            pqT + ((size_t)slice * 512 + tid) * 64 + q0);
        *reinterpret_cast<float4*>(&pql[tid][0]) = q4;
        const float s = wave_rsum(vv);
        if ((tid & 63) == 0) wsum[tid >> 6] = s;
    }
    __syncthreads();
    float sumv = 0.f;
#pragma unroll
    for (int w = 0; w < 8; ++w) sumv += wsum[w];

    // main loop: 128 n per thread, 4 q's
    const float* __restrict__ pkp = pkT + ((size_t)slice * 512 + nh * 128) * 128 + k;
    float a0 = 0.f, a1 = 0.f, a2 = 0.f, a3 = 0.f;
#pragma unroll 4
    for (int n = 0; n < 128; ++n) {
        const float pk = pkp[(size_t)n * 128];                     // coalesced
        const float4 pq4 = *reinterpret_cast<const float4*>(&pql[nh * 128 + n][0]);
        const float w = wl[nh * 128 + n];
        const float e0 = __builtin_amdgcn_exp2f(pq4.x + pk);
        const float e1 = __builtin_amdgcn_exp2f(pq4.y + pk);
        const float e2 = __builtin_amdgcn_exp2f(pq4.z + pk);
        const float e3 = __builtin_amdgcn_exp2f(pq4.w + pk);
        a0 = fmaf(w, __builtin_amdgcn_rcpf(e0 + 1.f), a0);
        a1 = fmaf(w, __builtin_amdgcn_rcpf(e1 + 1.f), a1);
        a2 = fmaf(w, __builtin_amdgcn_rcpf(e2 + 1.f), a2);
        a3 = fmaf(w, __builtin_amdgcn_rcpf(e3 + 1.f), a3);
    }
    if (nh) {
        partial[nh - 1][0][k] = a0; partial[nh - 1][1][k] = a1;
        partial[nh - 1][2][k] = a2; partial[nh - 1][3][k] = a3;
    }
    __syncthreads();
    if (!nh) {
        sc[0][k] = a0 + partial[0][0][k] + partial[1][0][k] + partial[2][0][k] + sumv;
        sc[1][k] = a1 + partial[0][1][k] + partial[1][1][k] + partial[2][1][k] + sumv;
        sc[2][k] = a2 + partial[0][2][k] + partial[1][2][k] + partial[2][2][k] + sumv;
        sc[3][k] = a3 + partial[0][3][k] + partial[1][3][k] + partial[2][3][k] + sumv;
    }
    __syncthreads();

    // softmax over k=128 per q; group j = nh handles q0+j (2 aligned waves)
    const int j = nh, kk = k;
    const float orig = sc[j][kk];
    float m = wave_rmax(orig);
    if ((tid & 63) == 0) wredm[tid >> 6] = m;
    __syncthreads();
    m = fmaxf(wredm[2 * j], wredm[2 * j + 1]);
    const float e = __builtin_amdgcn_exp2f((orig - m) * LOG2E);
    float s = wave_rsum(e);
    if ((tid & 63) == 0) wreds[tid >> 6] = s;
    __syncthreads();
    s = wreds[2 * j] + wreds[2 * j + 1];
    sc_out[((size_t)slice * 64 + q0 + j) * 128 + kk] = e * __builtin_amdgcn_rcpf(s);
}

// ---------------------------------------------------------------------------
// Context: ctx[q][n] = sum_k p[q][k] * keys[k][n]   (raw keys)
// Block: one (slice, q-tile of 4). 128 threads, float4 over n.
// ---------------------------------------------------------------------------
__global__ __launch_bounds__(128)
void context_kernel(const float* __restrict__ keys,  // [32][128][512]
                    const float* __restrict__ sc,    // [32][64][128]
                    float* __restrict__ ctx)         // [32][64][512]
{
    const int slice = blockIdx.x >> 4;
    const int q0    = (blockIdx.x & 15) * 4;
    const int tid   = threadIdx.x;   // n4 index

    __shared__ float pl[4][128];
#pragma unroll
    for (int i = 0; i < 4; ++i)
        pl[i][tid] = sc[((size_t)slice * 64 + q0 + i) * 128 + tid];
    __syncthreads();

    float4 acc0 = {0,0,0,0}, acc1 = {0,0,0,0}, acc2 = {0,0,0,0}, acc3 = {0,0,0,0};
    const float* __restrict__ kb = keys + (size_t)slice * 128 * 512 + tid * 4;
#pragma unroll 4
    for (int kkk = 0; kkk < 128; ++kkk) {
        const float4 kv = *reinterpret_cast<const float4*>(kb + (size_t)kkk * 512);
        const float p0 = pl[0][kkk], p1 = pl[1][kkk], p2 = pl[2][kkk], p3 = pl[3][kkk];
        acc0.x = fmaf(p0, kv.x, acc0.x); acc0.y = fmaf(p0, kv.y, acc0.y);
        acc0.z = fmaf(p0, kv.z, acc0.z); acc0.w = fmaf(p0, kv.w, acc0.w);
        acc1.x = fmaf(p1, kv.x, acc1.x); acc1.y = fmaf(p1, kv.y, acc1.y);
        acc1.z = fmaf(p1, kv.z, acc1.z); acc1.w = fmaf(p1, kv.w, acc1.w);
        acc2.x = fmaf(p2, kv.x, acc2.x); acc2.y = fmaf(p2, kv.y, acc2.y);
        acc2.z = fmaf(p2, kv.z, acc2.z); acc2.w = fmaf(p2, kv.w, acc2.w);
        acc3.x = fmaf(p3, kv.x, acc3.x); acc3.y = fmaf(p3, kv.y, acc3.y);
        acc3.z = fmaf(p3, kv.z, acc3.z); acc3.w = fmaf(p3, kv.w, acc3.w);
    }
    float* __restrict__ cb = ctx + ((size_t)slice * 64 + q0) * 512 + tid * 4;
    *reinterpret_cast<float4*>(cb +   0)       = acc0;
    *reinterpret_cast<float4*>(cb + 512)       = acc1;
    *reinterpret_cast<float4*>(cb + 2 * 512)   = acc2;
    *reinterpret_cast<float4*>(cb + 3 * 512)   = acc3;
}

// ---------------------------------------------------------------------------
extern "C" void kernel_launch(void* const* d_in, const int* in_sizes, int n_in,
                              void* d_out, int out_size, void* d_ws, size_t ws_size,
                              hipStream_t stream)
{
    const float* query = (const float*)d_in[0];   // [2][16][64][512]
    const float* keys  = (const float*)d_in[1];   // [2][16][128][512]
    const float* Wq    = (const float*)d_in[2];   // [2][512][512]
    const float* Wk    = (const float*)d_in[3];   // [2][512][512]
    const float* vatt  = (const float*)d_in[4];   // [512]

    float* ctx_out = (float*)d_out;                          // 1,048,576 f32
    float* sc_out  = ctx_out + (size_t)32 * 64 * 512;        //   131,072 f32

    float* pqT = (float*)d_ws;                               // 32*512*64  = 4MB
    float* pkT = pqT + (size_t)32 * 512 * 64;                // 32*512*128 = 8MB

    proj_kernel<64> <<<dim3(4, 16, 2), 256, 0, stream>>>(query, Wq, pqT);
    proj_kernel<128><<<dim3(8, 16, 2), 256, 0, stream>>>(keys,  Wk, pkT);
    score_softmax_kernel<<<dim3(512), 512, 0, stream>>>(pqT, pkT, vatt, sc_out);
    context_kernel<<<dim3(512), 128, 0, stream>>>(keys, sc_out, ctx_out);
}

// Round 2
// 99.318 us; speedup vs baseline: 4.9320x; 4.9320x over previous
//
#include <hip/hip_runtime.h>

// Problem dims (fixed by setup_inputs):
//   B=2, b=16, t_q=64, t_k=128, d=512 (qs=ks=nu), slices = B*b = 32
// d_out = context [32][64][512] (f32)  ++  scores_normalized [32][64][128] (f32)
// d_ws  = pqT [32][512][64] (4MB) ++ pkT [32][512][128] (8MB), both pre-scaled by 2*log2(e)

#define DEV_INLINE __device__ __forceinline__

constexpr float C2    = 2.8853900817779268f;  // 2*log2(e): exp2(C2*x) = e^{2x}
constexpr float LOG2E = 1.4426950408889634f;

// ---------------------------------------------------------------------------
// Fused projection GEMM (both pq and pk in one launch for occupancy).
//   Y[slice][n][t] = C2 * dot(X[row], W[n]),  X row-major [rows][512],
//   W (out,in) row-major per B.  64x64 output tile, K-step 16, 256 threads,
//   4x4 micro-tile. Thread layout: ni=tid&15 owns t (output-fastest dim,
//   coalesced stores), mi=tid>>4 owns n.
// Blocks 0..255: query (rows 2048, TK=64). Blocks 256..767: keys (rows 4096, TK=128).
// ---------------------------------------------------------------------------
__global__ __launch_bounds__(256)
void proj_tiled_kernel(const float* __restrict__ query, const float* __restrict__ keys,
                       const float* __restrict__ Wq,    const float* __restrict__ Wk,
                       float* __restrict__ pqT,         float* __restrict__ pkT)
{
    constexpr int LSTR = 68;                 // LDS row stride (floats): 64+4, keeps b128 align
    __shared__ __align__(16) float xs[16 * LSTR];
    __shared__ __align__(16) float ws[16 * LSTR];

    int bid = blockIdx.x;
    const float* X; const float* W; float* Y;
    int tkshift;                             // log2(TK)
    if (bid < 256) {
        const int mt = bid >> 3, nt = bid & 7;
        const int m0 = mt * 64;
        X = query + (size_t)m0 * 512;
        W = Wq + ((size_t)(m0 >> 10)) * 512 * 512 + (size_t)(nt * 64) * 512;
        Y = pqT;  tkshift = 6;
        bid = m0 | (nt << 20);               // pack m0, nt for epilogue
    } else {
        const int b2 = bid - 256;
        const int mt = b2 >> 3, nt = b2 & 7;
        const int m0 = mt * 64;
        X = keys + (size_t)m0 * 512;
        W = Wk + ((size_t)(m0 >> 11)) * 512 * 512 + (size_t)(nt * 64) * 512;
        Y = pkT;  tkshift = 7;
        bid = m0 | (nt << 20);
    }
    const int m0 = bid & 0xFFFFF, nt = bid >> 20;
    const int tid = threadIdx.x;
    const int ni = tid & 15;                 // t-group (output fastest dim)
    const int mi = tid >> 4;                 // n-group

    // staging assignment: 64 rows x 16 k, one float4 per thread per array
    const int srow = tid >> 2, sk4 = (tid & 3) * 4;
    const float* Xp = X + (size_t)srow * 512 + sk4;
    const float* Wp = W + (size_t)srow * 512 + sk4;

    float acc[4][4];
#pragma unroll
    for (int i = 0; i < 4; ++i)
#pragma unroll
        for (int j = 0; j < 4; ++j) acc[i][j] = 0.f;

    float4 xa = *reinterpret_cast<const float4*>(Xp);
    float4 wa = *reinterpret_cast<const float4*>(Wp);

    for (int ks = 0; ks < 32; ++ks) {
        // write staged regs to LDS (2-way bank aliasing only -> free)
        xs[(sk4 + 0) * LSTR + srow] = xa.x;
        xs[(sk4 + 1) * LSTR + srow] = xa.y;
        xs[(sk4 + 2) * LSTR + srow] = xa.z;
        xs[(sk4 + 3) * LSTR + srow] = xa.w;
        ws[(sk4 + 0) * LSTR + srow] = wa.x;
        ws[(sk4 + 1) * LSTR + srow] = wa.y;
        ws[(sk4 + 2) * LSTR + srow] = wa.z;
        ws[(sk4 + 3) * LSTR + srow] = wa.w;
        __syncthreads();
        if (ks < 31) {                        // prefetch next K-slab (hidden under compute)
            xa = *reinterpret_cast<const float4*>(Xp + (ks + 1) * 16);
            wa = *reinterpret_cast<const float4*>(Wp + (ks + 1) * 16);
        }
#pragma unroll
        for (int kk = 0; kk < 16; ++kk) {
            const float4 a = *reinterpret_cast<const float4*>(&xs[kk * LSTR + ni * 4]);
            const float4 b = *reinterpret_cast<const float4*>(&ws[kk * LSTR + mi * 4]);
            const float av[4] = {a.x, a.y, a.z, a.w};
            const float bv[4] = {b.x, b.y, b.z, b.w};
#pragma unroll
            for (int i = 0; i < 4; ++i)
#pragma unroll
                for (int j = 0; j < 4; ++j)
                    acc[i][j] = fmaf(bv[i], av[j], acc[i][j]);
        }
        __syncthreads();
    }

    // epilogue: Y[slice][n][t], slice = m0>>tkshift, t = (m0 & (TK-1)) + local t
    const int TK = 1 << tkshift;
    const int slice = m0 >> tkshift;
    const int tbase = (m0 & (TK - 1)) + ni * 4;
    float* Yp = Y + ((size_t)(slice * 512 + nt * 64 + mi * 4) << tkshift) + tbase;
#pragma unroll
    for (int i = 0; i < 4; ++i) {
        float4 o;
        o.x = acc[i][0] * C2; o.y = acc[i][1] * C2;
        o.z = acc[i][2] * C2; o.w = acc[i][3] * C2;
        *reinterpret_cast<float4*>(Yp + ((size_t)i << tkshift)) = o;
    }
}

// ---------------------------------------------------------------------------
// Fused score + softmax.
// score[q][k] = sum_n v_n * tanh(pq[q][n]+pk[k][n])
//             = sum_v + sum_n (-2 v_n) * rcp(1 + exp2(pqs+pks))   [pqs,pks pre-scaled]
// Block: one (slice, q-tile of 4). 512 threads: k = tid&127, nh = tid>>7 (n-quarter).
// ---------------------------------------------------------------------------
DEV_INLINE float wave_rmax(float v) {
#pragma unroll
    for (int off = 32; off; off >>= 1) v = fmaxf(v, __shfl_xor(v, off, 64));
    return v;
}
DEV_INLINE float wave_rsum(float v) {
#pragma unroll
    for (int off = 32; off; off >>= 1) v += __shfl_xor(v, off, 64);
    return v;
}

__global__ __launch_bounds__(512)
void score_softmax_kernel(const float* __restrict__ pqT,   // [32][512][64]
                          const float* __restrict__ pkT,   // [32][512][128]
                          const float* __restrict__ vatt,  // [512]
                          float* __restrict__ sc_out)      // [32][64][128]
{
    const int slice = blockIdx.x >> 4;
    const int q0    = (blockIdx.x & 15) * 4;
    const int tid   = threadIdx.x;
    const int k     = tid & 127;
    const int nh    = tid >> 7;   // 0..3

    __shared__ __align__(16) float pql[512][4];   // pql[n][j]
    __shared__ float wl[512];                     // -2*v
    __shared__ float partial[3][4][128];
    __shared__ float sc[4][128];
    __shared__ float wredm[8], wreds[8], wsum[8];

    // stage pq tile (transposed layout makes this a single float4 per thread),
    // w = -2*v, and block-reduce sum_v
    {
        const float vv = vatt[tid];
        wl[tid] = -2.f * vv;
        const float4 q4 = *reinterpret_cast<const float4*>(
            pqT + ((size_t)slice * 512 + tid) * 64 + q0);
        *reinterpret_cast<float4*>(&pql[tid][0]) = q4;
        const float s = wave_rsum(vv);
        if ((tid & 63) == 0) wsum[tid >> 6] = s;
    }
    __syncthreads();
    float sumv = 0.f;
#pragma unroll
    for (int w = 0; w < 8; ++w) sumv += wsum[w];

    // main loop: 128 n per thread, 4 q's
    const float* __restrict__ pkp = pkT + ((size_t)slice * 512 + nh * 128) * 128 + k;
    float a0 = 0.f, a1 = 0.f, a2 = 0.f, a3 = 0.f;
#pragma unroll 4
    for (int n = 0; n < 128; ++n) {
        const float pk = pkp[(size_t)n * 128];                     // coalesced
        const float4 pq4 = *reinterpret_cast<const float4*>(&pql[nh * 128 + n][0]);
        const float w = wl[nh * 128 + n];
        const float e0 = __builtin_amdgcn_exp2f(pq4.x + pk);
        const float e1 = __builtin_amdgcn_exp2f(pq4.y + pk);
        const float e2 = __builtin_amdgcn_exp2f(pq4.z + pk);
        const float e3 = __builtin_amdgcn_exp2f(pq4.w + pk);
        a0 = fmaf(w, __builtin_amdgcn_rcpf(e0 + 1.f), a0);
        a1 = fmaf(w, __builtin_amdgcn_rcpf(e1 + 1.f), a1);
        a2 = fmaf(w, __builtin_amdgcn_rcpf(e2 + 1.f), a2);
        a3 = fmaf(w, __builtin_amdgcn_rcpf(e3 + 1.f), a3);
    }
    if (nh) {
        partial[nh - 1][0][k] = a0; partial[nh - 1][1][k] = a1;
        partial[nh - 1][2][k] = a2; partial[nh - 1][3][k] = a3;
    }
    __syncthreads();
    if (!nh) {
        sc[0][k] = a0 + partial[0][0][k] + partial[1][0][k] + partial[2][0][k] + sumv;
        sc[1][k] = a1 + partial[0][1][k] + partial[1][1][k] + partial[2][1][k] + sumv;
        sc[2][k] = a2 + partial[0][2][k] + partial[1][2][k] + partial[2][2][k] + sumv;
        sc[3][k] = a3 + partial[0][3][k] + partial[1][3][k] + partial[2][3][k] + sumv;
    }
    __syncthreads();

    // softmax over k=128 per q; group j = nh handles q0+j (2 aligned waves)
    const int j = nh, kk = k;
    const float orig = sc[j][kk];
    float m = wave_rmax(orig);
    if ((tid & 63) == 0) wredm[tid >> 6] = m;
    __syncthreads();
    m = fmaxf(wredm[2 * j], wredm[2 * j + 1]);
    const float e = __builtin_amdgcn_exp2f((orig - m) * LOG2E);
    float s = wave_rsum(e);
    if ((tid & 63) == 0) wreds[tid >> 6] = s;
    __syncthreads();
    s = wreds[2 * j] + wreds[2 * j + 1];
    sc_out[((size_t)slice * 64 + q0 + j) * 128 + kk] = e * __builtin_amdgcn_rcpf(s);
}

// ---------------------------------------------------------------------------
// Context: ctx[q][n] = sum_k p[q][k] * keys[k][n]   (raw keys)
// Block: one (slice, q-tile of 4). 128 threads, float4 over n.
// ---------------------------------------------------------------------------
__global__ __launch_bounds__(128)
void context_kernel(const float* __restrict__ keys,  // [32][128][512]
                    const float* __restrict__ sc,    // [32][64][128]
                    float* __restrict__ ctx)         // [32][64][512]
{
    const int slice = blockIdx.x >> 4;
    const int q0    = (blockIdx.x & 15) * 4;
    const int tid   = threadIdx.x;   // n4 index

    __shared__ float pl[4][128];
#pragma unroll
    for (int i = 0; i < 4; ++i)
        pl[i][tid] = sc[((size_t)slice * 64 + q0 + i) * 128 + tid];
    __syncthreads();

    float4 acc0 = {0,0,0,0}, acc1 = {0,0,0,0}, acc2 = {0,0,0,0}, acc3 = {0,0,0,0};
    const float* __restrict__ kb = keys + (size_t)slice * 128 * 512 + tid * 4;
#pragma unroll 4
    for (int kkk = 0; kkk < 128; ++kkk) {
        const float4 kv = *reinterpret_cast<const float4*>(kb + (size_t)kkk * 512);
        const float p0 = pl[0][kkk], p1 = pl[1][kkk], p2 = pl[2][kkk], p3 = pl[3][kkk];
        acc0.x = fmaf(p0, kv.x, acc0.x); acc0.y = fmaf(p0, kv.y, acc0.y);
        acc0.z = fmaf(p0, kv.z, acc0.z); acc0.w = fmaf(p0, kv.w, acc0.w);
        acc1.x = fmaf(p1, kv.x, acc1.x); acc1.y = fmaf(p1, kv.y, acc1.y);
        acc1.z = fmaf(p1, kv.z, acc1.z); acc1.w = fmaf(p1, kv.w, acc1.w);
        acc2.x = fmaf(p2, kv.x, acc2.x); acc2.y = fmaf(p2, kv.y, acc2.y);
        acc2.z = fmaf(p2, kv.z, acc2.z); acc2.w = fmaf(p2, kv.w, acc2.w);
        acc3.x = fmaf(p3, kv.x, acc3.x); acc3.y = fmaf(p3, kv.y, acc3.y);
        acc3.z = fmaf(p3, kv.z, acc3.z); acc3.w = fmaf(p3, kv.w, acc3.w);
    }
    float* __restrict__ cb = ctx + ((size_t)slice * 64 + q0) * 512 + tid * 4;
    *reinterpret_cast<float4*>(cb +   0)       = acc0;
    *reinterpret_cast<float4*>(cb + 512)       = acc1;
    *reinterpret_cast<float4*>(cb + 2 * 512)   = acc2;
    *reinterpret_cast<float4*>(cb + 3 * 512)   = acc3;
}

// ---------------------------------------------------------------------------
extern "C" void kernel_launch(void* const* d_in, const int* in_sizes, int n_in,
                              void* d_out, int out_size, void* d_ws, size_t ws_size,
                              hipStream_t stream)
{
    const float* query = (const float*)d_in[0];   // [2][16][64][512]
    const float* keys  = (const float*)d_in[1];   // [2][16][128][512]
    const float* Wq    = (const float*)d_in[2];   // [2][512][512]
    const float* Wk    = (const float*)d_in[3];   // [2][512][512]
    const float* vatt  = (const float*)d_in[4];   // [512]

    float* ctx_out = (float*)d_out;                          // 1,048,576 f32
    float* sc_out  = ctx_out + (size_t)32 * 64 * 512;        //   131,072 f32

    float* pqT = (float*)d_ws;                               // 32*512*64  = 4MB
    float* pkT = pqT + (size_t)32 * 512 * 64;                // 32*512*128 = 8MB

    proj_tiled_kernel<<<dim3(768), 256, 0, stream>>>(query, keys, Wq, Wk, pqT, pkT);
    score_softmax_kernel<<<dim3(512), 512, 0, stream>>>(pqT, pkT, vatt, sc_out);
    context_kernel<<<dim3(512), 128, 0, stream>>>(keys, sc_out, ctx_out);
}

// Round 4
// 73.650 us; speedup vs baseline: 6.6509x; 1.3485x over previous
//
#include <hip/hip_runtime.h>

// Problem dims (fixed by setup_inputs):
//   B=2, b=16, t_q=64, t_k=128, d=512 (qs=ks=nu), slices = B*b = 32
// d_out = context [32][64][512] (f32)  ++  scores_normalized [32][64][128] (f32)
// d_ws  = pqT [32][512][64] (4MB) ++ pkT [32][512][128] (8MB), pre-scaled by 2*log2(e)

#define DEV_INLINE __device__ __forceinline__

constexpr float C2    = 2.8853900817779268f;  // 2*log2(e): exp2(C2*x) = e^{2x}
constexpr float LOG2E = 1.4426950408889634f;

typedef _Float16 f16x8 __attribute__((ext_vector_type(8)));
typedef float    f32x16 __attribute__((ext_vector_type(16)));

DEV_INLINE unsigned int pk2(float a, float b) {
    auto h = __builtin_amdgcn_cvt_pkrtz(a, b);   // __fp16x2 on this toolchain
    return __builtin_bit_cast(unsigned int, h);
}

// ---------------------------------------------------------------------------
// fp16 MFMA projection GEMM.  Y[slice][n][t] = C2 * dot(X[t-row], W[n-row]).
// MFMA operands SWAPPED: A = W-tile (M=n), B = X-tile (N=t) so D cols (lane&31)
// map to t -> coalesced transposed stores.
// Tile 128(M) x 128(N), BK=32, 8 waves (2M x 4N), wave-tile 64x32, frags 32x32x16.
// LDS: Ws[128][32] f16 + Xs[128][32] f16, XOR-swizzled (byte ^= ((row>>1)&3)<<4).
// Blocks 0..63: query-GEMM (TK=64). Blocks 64..191: keys-GEMM (TK=128).
// ---------------------------------------------------------------------------
__global__ __launch_bounds__(512)
void proj_mfma_kernel(const float* __restrict__ query, const float* __restrict__ keys,
                      const float* __restrict__ Wq,    const float* __restrict__ Wk,
                      float* __restrict__ pqT,         float* __restrict__ pkT)
{
    __shared__ __align__(16) unsigned char smem[16384];   // Ws @0 (8KB), Xs @8192

    const int bid = blockIdx.x;
    const float* X; const float* W; float* Y;
    int tkshift, Bi, mt, ntile;
    if (bid < 64) {
        Bi = bid >> 5; mt = (bid >> 3) & 3; ntile = bid & 7;
        X = query + ((size_t)Bi * 1024 + ntile * 128) * 512;
        W = Wq + (size_t)Bi * 512 * 512 + (size_t)mt * 128 * 512;
        Y = pqT; tkshift = 6;
    } else {
        const int b2 = bid - 64;
        Bi = b2 >> 6; mt = (b2 >> 4) & 3; ntile = b2 & 15;
        X = keys + ((size_t)Bi * 2048 + ntile * 128) * 512;
        W = Wk + (size_t)Bi * 512 * 512 + (size_t)mt * 128 * 512;
        Y = pkT; tkshift = 7;
    }

    const int tid  = threadIdx.x;
    // staging: thread -> (row, 16B slot), 2 float4 global loads per array
    const int srow = tid >> 2, ss = tid & 3;
    const float* Wp = W + (size_t)srow * 512 + ss * 8;
    const float* Xp = X + (size_t)srow * 512 + ss * 8;
    const int wrbyte = srow * 64 + ((ss * 16) ^ (((srow >> 1) & 3) << 4));

    // wave decomposition
    const int wid = tid >> 6, lane = tid & 63;
    const int wm = wid >> 2, wn = wid & 3;        // 2 x 4 wave grid
    const int r31 = lane & 31, h = lane >> 5;

    // LDS read byte offsets (swizzle matches write side)
    const int rowA0 = wm * 64 + r31, rowA1 = rowA0 + 32;
    const int rowB  = wn * 32 + r31;
    const int a00 = rowA0 * 64 + (((0 * 2 + h) * 16) ^ (((rowA0 >> 1) & 3) << 4));
    const int a01 = rowA0 * 64 + (((1 * 2 + h) * 16) ^ (((rowA0 >> 1) & 3) << 4));
    const int a10 = rowA1 * 64 + (((0 * 2 + h) * 16) ^ (((rowA1 >> 1) & 3) << 4));
    const int a11 = rowA1 * 64 + (((1 * 2 + h) * 16) ^ (((rowA1 >> 1) & 3) << 4));
    const int b0  = 8192 + rowB * 64 + (((0 * 2 + h) * 16) ^ (((rowB >> 1) & 3) << 4));
    const int b1  = 8192 + rowB * 64 + (((1 * 2 + h) * 16) ^ (((rowB >> 1) & 3) << 4));

    f32x16 acc0, acc1;
#pragma unroll
    for (int i = 0; i < 16; ++i) { acc0[i] = 0.f; acc1[i] = 0.f; }

    // prologue: load K-step 0
    float4 wa0 = *reinterpret_cast<const float4*>(Wp);
    float4 wa1 = *reinterpret_cast<const float4*>(Wp + 4);
    float4 xa0 = *reinterpret_cast<const float4*>(Xp);
    float4 xa1 = *reinterpret_cast<const float4*>(Xp + 4);

    for (int ks = 0; ks < 16; ++ks) {
        uint4 uw, ux;
        uw.x = pk2(wa0.x, wa0.y); uw.y = pk2(wa0.z, wa0.w);
        uw.z = pk2(wa1.x, wa1.y); uw.w = pk2(wa1.z, wa1.w);
        ux.x = pk2(xa0.x, xa0.y); ux.y = pk2(xa0.z, xa0.w);
        ux.z = pk2(xa1.x, xa1.y); ux.w = pk2(xa1.z, xa1.w);
        *reinterpret_cast<uint4*>(smem + wrbyte)        = uw;
        *reinterpret_cast<uint4*>(smem + 8192 + wrbyte) = ux;
        __syncthreads();

        if (ks < 15) {   // prefetch next K-slab; latency hides under MFMA phase
            const int ko = (ks + 1) * 32;
            wa0 = *reinterpret_cast<const float4*>(Wp + ko);
            wa1 = *reinterpret_cast<const float4*>(Wp + ko + 4);
            xa0 = *reinterpret_cast<const float4*>(Xp + ko);
            xa1 = *reinterpret_cast<const float4*>(Xp + ko + 4);
        }

        const f16x8 fa00 = *reinterpret_cast<const f16x8*>(smem + a00);
        const f16x8 fa01 = *reinterpret_cast<const f16x8*>(smem + a01);
        const f16x8 fa10 = *reinterpret_cast<const f16x8*>(smem + a10);
        const f16x8 fa11 = *reinterpret_cast<const f16x8*>(smem + a11);
        const f16x8 fb0  = *reinterpret_cast<const f16x8*>(smem + b0);
        const f16x8 fb1  = *reinterpret_cast<const f16x8*>(smem + b1);

        acc0 = __builtin_amdgcn_mfma_f32_32x32x16_f16(fa00, fb0, acc0, 0, 0, 0);
        acc0 = __builtin_amdgcn_mfma_f32_32x32x16_f16(fa01, fb1, acc0, 0, 0, 0);
        acc1 = __builtin_amdgcn_mfma_f32_32x32x16_f16(fa10, fb0, acc1, 0, 0, 0);
        acc1 = __builtin_amdgcn_mfma_f32_32x32x16_f16(fa11, fb1, acc1, 0, 0, 0);
        __syncthreads();
    }

    // epilogue: D col (lane&31) = t dim; row = (reg&3)+8*(reg>>2)+4*h = n dim
    const int TK = 1 << tkshift;
    const int nr = ntile * 128 + wn * 32 + r31;      // within-B X-row index
    const int slice = Bi * 16 + (nr >> tkshift);
    const int t = nr & (TK - 1);
    const int nf0 = mt * 128 + wm * 64 + 4 * h;
#pragma unroll
    for (int ab = 0; ab < 2; ++ab) {
        const f32x16 acc = ab ? acc1 : acc0;
#pragma unroll
        for (int reg = 0; reg < 16; ++reg) {
            const int nf = nf0 + ab * 32 + (reg & 3) + 8 * (reg >> 2);
            Y[((size_t)(slice * 512 + nf) << tkshift) + t] = acc[reg] * C2;
        }
    }
}

// ---------------------------------------------------------------------------
// Fused score + softmax (unchanged).
// score[q][k] = sum_v + sum_n (-2 v_n) * rcp(1 + exp2(pqs+pks))
// ---------------------------------------------------------------------------
DEV_INLINE float wave_rmax(float v) {
#pragma unroll
    for (int off = 32; off; off >>= 1) v = fmaxf(v, __shfl_xor(v, off, 64));
    return v;
}
DEV_INLINE float wave_rsum(float v) {
#pragma unroll
    for (int off = 32; off; off >>= 1) v += __shfl_xor(v, off, 64);
    return v;
}

__global__ __launch_bounds__(512)
void score_softmax_kernel(const float* __restrict__ pqT,   // [32][512][64]
                          const float* __restrict__ pkT,   // [32][512][128]
                          const float* __restrict__ vatt,  // [512]
                          float* __restrict__ sc_out)      // [32][64][128]
{
    const int slice = blockIdx.x >> 4;
    const int q0    = (blockIdx.x & 15) * 4;
    const int tid   = threadIdx.x;
    const int k     = tid & 127;
    const int nh    = tid >> 7;   // 0..3

    __shared__ __align__(16) float pql[512][4];   // pql[n][j]
    __shared__ float wl[512];                     // -2*v
    __shared__ float partial[3][4][128];
    __shared__ float sc[4][128];
    __shared__ float wredm[8], wreds[8], wsum[8];

    {
        const float vv = vatt[tid];
        wl[tid] = -2.f * vv;
        const float4 q4 = *reinterpret_cast<const float4*>(
            pqT + ((size_t)slice * 512 + tid) * 64 + q0);
        *reinterpret_cast<float4*>(&pql[tid][0]) = q4;
        const float s = wave_rsum(vv);
        if ((tid & 63) == 0) wsum[tid >> 6] = s;
    }
    __syncthreads();
    float sumv = 0.f;
#pragma unroll
    for (int w = 0; w < 8; ++w) sumv += wsum[w];

    const float* __restrict__ pkp = pkT + ((size_t)slice * 512 + nh * 128) * 128 + k;
    float a0 = 0.f, a1 = 0.f, a2 = 0.f, a3 = 0.f;
#pragma unroll 4
    for (int n = 0; n < 128; ++n) {
        const float pk = pkp[(size_t)n * 128];                     // coalesced
        const float4 pq4 = *reinterpret_cast<const float4*>(&pql[nh * 128 + n][0]);
        const float w = wl[nh * 128 + n];
        const float e0 = __builtin_amdgcn_exp2f(pq4.x + pk);
        const float e1 = __builtin_amdgcn_exp2f(pq4.y + pk);
        const float e2 = __builtin_amdgcn_exp2f(pq4.z + pk);
        const float e3 = __builtin_amdgcn_exp2f(pq4.w + pk);
        a0 = fmaf(w, __builtin_amdgcn_rcpf(e0 + 1.f), a0);
        a1 = fmaf(w, __builtin_amdgcn_rcpf(e1 + 1.f), a1);
        a2 = fmaf(w, __builtin_amdgcn_rcpf(e2 + 1.f), a2);
        a3 = fmaf(w, __builtin_amdgcn_rcpf(e3 + 1.f), a3);
    }
    if (nh) {
        partial[nh - 1][0][k] = a0; partial[nh - 1][1][k] = a1;
        partial[nh - 1][2][k] = a2; partial[nh - 1][3][k] = a3;
    }
    __syncthreads();
    if (!nh) {
        sc[0][k] = a0 + partial[0][0][k] + partial[1][0][k] + partial[2][0][k] + sumv;
        sc[1][k] = a1 + partial[0][1][k] + partial[1][1][k] + partial[2][1][k] + sumv;
        sc[2][k] = a2 + partial[0][2][k] + partial[1][2][k] + partial[2][2][k] + sumv;
        sc[3][k] = a3 + partial[0][3][k] + partial[1][3][k] + partial[2][3][k] + sumv;
    }
    __syncthreads();

    const int j = nh, kk = k;
    const float orig = sc[j][kk];
    float m = wave_rmax(orig);
    if ((tid & 63) == 0) wredm[tid >> 6] = m;
    __syncthreads();
    m = fmaxf(wredm[2 * j], wredm[2 * j + 1]);
    const float e = __builtin_amdgcn_exp2f((orig - m) * LOG2E);
    float s = wave_rsum(e);
    if ((tid & 63) == 0) wreds[tid >> 6] = s;
    __syncthreads();
    s = wreds[2 * j] + wreds[2 * j + 1];
    sc_out[((size_t)slice * 64 + q0 + j) * 128 + kk] = e * __builtin_amdgcn_rcpf(s);
}

// ---------------------------------------------------------------------------
// Context: ctx[q][n] = sum_k p[q][k] * keys[k][n]   (raw keys)  — unchanged.
// ---------------------------------------------------------------------------
__global__ __launch_bounds__(128)
void context_kernel(const float* __restrict__ keys,  // [32][128][512]
                    const float* __restrict__ sc,    // [32][64][128]
                    float* __restrict__ ctx)         // [32][64][512]
{
    const int slice = blockIdx.x >> 4;
    const int q0    = (blockIdx.x & 15) * 4;
    const int tid   = threadIdx.x;   // n4 index

    __shared__ float pl[4][128];
#pragma unroll
    for (int i = 0; i < 4; ++i)
        pl[i][tid] = sc[((size_t)slice * 64 + q0 + i) * 128 + tid];
    __syncthreads();

    float4 acc0 = {0,0,0,0}, acc1 = {0,0,0,0}, acc2 = {0,0,0,0}, acc3 = {0,0,0,0};
    const float* __restrict__ kb = keys + (size_t)slice * 128 * 512 + tid * 4;
#pragma unroll 4
    for (int kkk = 0; kkk < 128; ++kkk) {
        const float4 kv = *reinterpret_cast<const float4*>(kb + (size_t)kkk * 512);
        const float p0 = pl[0][kkk], p1 = pl[1][kkk], p2 = pl[2][kkk], p3 = pl[3][kkk];
        acc0.x = fmaf(p0, kv.x, acc0.x); acc0.y = fmaf(p0, kv.y, acc0.y);
        acc0.z = fmaf(p0, kv.z, acc0.z); acc0.w = fmaf(p0, kv.w, acc0.w);
        acc1.x = fmaf(p1, kv.x, acc1.x); acc1.y = fmaf(p1, kv.y, acc1.y);
        acc1.z = fmaf(p1, kv.z, acc1.z); acc1.w = fmaf(p1, kv.w, acc1.w);
        acc2.x = fmaf(p2, kv.x, acc2.x); acc2.y = fmaf(p2, kv.y, acc2.y);
        acc2.z = fmaf(p2, kv.z, acc2.z); acc2.w = fmaf(p2, kv.w, acc2.w);
        acc3.x = fmaf(p3, kv.x, acc3.x); acc3.y = fmaf(p3, kv.y, acc3.y);
        acc3.z = fmaf(p3, kv.z, acc3.z); acc3.w = fmaf(p3, kv.w, acc3.w);
    }
    float* __restrict__ cb = ctx + ((size_t)slice * 64 + q0) * 512 + tid * 4;
    *reinterpret_cast<float4*>(cb +   0)       = acc0;
    *reinterpret_cast<float4*>(cb + 512)       = acc1;
    *reinterpret_cast<float4*>(cb + 2 * 512)   = acc2;
    *reinterpret_cast<float4*>(cb + 3 * 512)   = acc3;
}

// ---------------------------------------------------------------------------
extern "C" void kernel_launch(void* const* d_in, const int* in_sizes, int n_in,
                              void* d_out, int out_size, void* d_ws, size_t ws_size,
                              hipStream_t stream)
{
    const float* query = (const float*)d_in[0];   // [2][16][64][512]
    const float* keys  = (const float*)d_in[1];   // [2][16][128][512]
    const float* Wq    = (const float*)d_in[2];   // [2][512][512]
    const float* Wk    = (const float*)d_in[3];   // [2][512][512]
    const float* vatt  = (const float*)d_in[4];   // [512]

    float* ctx_out = (float*)d_out;                          // 1,048,576 f32
    float* sc_out  = ctx_out + (size_t)32 * 64 * 512;        //   131,072 f32

    float* pqT = (float*)d_ws;                               // 32*512*64  = 4MB
    float* pkT = pqT + (size_t)32 * 512 * 64;                // 32*512*128 = 8MB

    proj_mfma_kernel<<<dim3(192), 512, 0, stream>>>(query, keys, Wq, Wk, pqT, pkT);
    score_softmax_kernel<<<dim3(512), 512, 0, stream>>>(pqT, pkT, vatt, sc_out);
    context_kernel<<<dim3(512), 128, 0, stream>>>(keys, sc_out, ctx_out);
}

// Round 5
// 67.833 us; speedup vs baseline: 7.2212x; 1.0857x over previous
//
#include <hip/hip_runtime.h>

// Problem dims: B=2, b=16, t_q=64, t_k=128, d=512, slices = 32
// d_out = context [32][64][512] f32 ++ scores_normalized [32][64][128] f32
// d_ws  = pqT [32][512][64] (4MB) ++ pkT [32][512][128] (8MB) ++ X16 (8MB f16)
//   X16 layout (f16 units): query16 @0 | keys16 @1048576 | Wq16 @3145728 | Wk16 @3670016

#define DEV_INLINE __device__ __forceinline__

constexpr float C2    = 2.8853900817779268f;  // 2*log2(e)
constexpr float LOG2E = 1.4426950408889634f;

typedef _Float16 f16x8 __attribute__((ext_vector_type(8)));
typedef float    f32x16 __attribute__((ext_vector_type(16)));

DEV_INLINE unsigned int pk2(float a, float b) {
    auto h = __builtin_amdgcn_cvt_pkrtz(a, b);
    return __builtin_bit_cast(unsigned int, h);
}

#define GL2LDS16(g, l) __builtin_amdgcn_global_load_lds( \
    (const __attribute__((address_space(1))) void*)(g),  \
    (__attribute__((address_space(3))) void*)(l), 16, 0, 0)

// ---------------------------------------------------------------------------
// One-shot f32 -> f16 conversion of all GEMM operands (BW-bound).
// ---------------------------------------------------------------------------
__global__ __launch_bounds__(256)
void cvt_f16_kernel(const float* __restrict__ query, const float* __restrict__ keys,
                    const float* __restrict__ Wq,    const float* __restrict__ Wk,
                    uint2* __restrict__ dst)      // 1,048,576 float4 -> uint2(4 f16)
{
    const int i4 = blockIdx.x * 256 + threadIdx.x;      // 0 .. 1,048,575
    const float* src; int base;
    if (i4 < 262144)      { src = query; base = 0; }
    else if (i4 < 786432) { src = keys;  base = 262144; }
    else if (i4 < 917504) { src = Wq;    base = 786432; }
    else                  { src = Wk;    base = 917504; }
    const float4 v = *reinterpret_cast<const float4*>(src + (size_t)(i4 - base) * 4);
    dst[i4] = make_uint2(pk2(v.x, v.y), pk2(v.z, v.w));
}

// ---------------------------------------------------------------------------
// fp16 MFMA projection GEMM, global_load_lds staging, double-buffered LDS.
// Y[slice][n][t] = C2 * dot(X[t-row], W[n-row]).  A = W (M=n), B = X (N=t).
// Tile 128(M) x 64(N), BK=32, 256 threads (4 waves, 2M x 2N), frags 32x32x16.
// LDS per buf: A[128 rows][4 slots of 8 f16] 8KB + B[64][4] 4KB, XOR-swizzled
// via pre-swizzled GLOBAL source (linear LDS dest) + swizzled ds_read.
// Blocks 0..127: query (TK=64). Blocks 128..383: keys (TK=128).
// ---------------------------------------------------------------------------
__global__ __launch_bounds__(256)
void proj_mfma_kernel(const _Float16* __restrict__ X16,
                      float* __restrict__ pqT, float* __restrict__ pkT)
{
    __shared__ __align__(16) unsigned char smem[24576];   // 2 x (A 8KB + B 4KB)

    const int bid = blockIdx.x;
    int Bi, mt, tt, tkshift;
    const _Float16 *Wb, *Xb; float* Y;
    if (bid < 128) {      // query GEMM
        Bi = bid >> 6; mt = (bid >> 4) & 3; tt = bid & 15;
        Xb = X16 + ((size_t)Bi * 1024 + tt * 64) * 512;
        Wb = X16 + 3145728 + (size_t)Bi * 262144 + (size_t)(mt * 128) * 512;
        Y = pqT; tkshift = 6;
    } else {              // keys GEMM
        const int b2 = bid - 128;
        Bi = b2 >> 7; mt = (b2 >> 5) & 3; tt = b2 & 31;
        Xb = X16 + 1048576 + ((size_t)Bi * 2048 + tt * 64) * 512;
        Wb = X16 + 3670016 + (size_t)Bi * 262144 + (size_t)(mt * 128) * 512;
        Y = pkT; tkshift = 7;
    }
    const int tid = threadIdx.x;

    // staging: linear LDS u -> global (row = u>>2, actual slot = (u&3) ^ ((row>>1)&3))
    auto srcoff = [](int u) {
        const int row = u >> 2, s = (u & 3) ^ ((row >> 1) & 3);
        return (size_t)row * 512 + s * 8;
    };
    const _Float16* gA0 = Wb + srcoff(tid);         // A rows 0..63
    const _Float16* gA1 = Wb + srcoff(tid + 256);   // A rows 64..127
    const _Float16* gB  = Xb + srcoff(tid);         // B rows 0..63
    unsigned char* const ldsA0 = smem + tid * 16;
    unsigned char* const ldsA1 = smem + 4096 + tid * 16;
    unsigned char* const ldsB  = smem + 8192 + tid * 16;

    // wave decomposition / fragment read offsets (swizzle matches source perm)
    const int wid = tid >> 6, lane = tid & 63;
    const int wm = wid >> 1, wn = wid & 1;
    const int r31 = lane & 31, h = lane >> 5;
    auto lofs = [](int row, int slot) {
        return row * 64 + ((slot ^ ((row >> 1) & 3)) * 16);
    };
    const int rowA0 = wm * 64 + r31, rowA1 = rowA0 + 32, rowB = wn * 32 + r31;
    const int a00 = lofs(rowA0, h),     a01 = lofs(rowA0, 2 + h);
    const int a10 = lofs(rowA1, h),     a11 = lofs(rowA1, 2 + h);
    const int b0  = 8192 + lofs(rowB, h), b1 = 8192 + lofs(rowB, 2 + h);

    f32x16 acc0, acc1;
#pragma unroll
    for (int i = 0; i < 16; ++i) { acc0[i] = 0.f; acc1[i] = 0.f; }

    // prologue: stage K-step 0 into buf0
    GL2LDS16(gA0, ldsA0);
    GL2LDS16(gA1, ldsA1);
    GL2LDS16(gB,  ldsB);
    asm volatile("s_waitcnt vmcnt(0)" ::: "memory");
    __builtin_amdgcn_s_barrier();

    for (int ks = 0; ks < 16; ++ks) {
        const int buf = ks & 1;
        if (ks < 15) {                       // stage next K-step into other buf
            const int ko = (ks + 1) * 32, bo = (buf ^ 1) * 12288;
            GL2LDS16(gA0 + ko, ldsA0 + bo);
            GL2LDS16(gA1 + ko, ldsA1 + bo);
            GL2LDS16(gB  + ko, ldsB  + bo);
        }
        const unsigned char* sb = smem + buf * 12288;
        const f16x8 fa00 = *reinterpret_cast<const f16x8*>(sb + a00);
        const f16x8 fa01 = *reinterpret_cast<const f16x8*>(sb + a01);
        const f16x8 fa10 = *reinterpret_cast<const f16x8*>(sb + a10);
        const f16x8 fa11 = *reinterpret_cast<const f16x8*>(sb + a11);
        const f16x8 fb0  = *reinterpret_cast<const f16x8*>(sb + b0);
        const f16x8 fb1  = *reinterpret_cast<const f16x8*>(sb + b1);
        acc0 = __builtin_amdgcn_mfma_f32_32x32x16_f16(fa00, fb0, acc0, 0, 0, 0);
        acc0 = __builtin_amdgcn_mfma_f32_32x32x16_f16(fa01, fb1, acc0, 0, 0, 0);
        acc1 = __builtin_amdgcn_mfma_f32_32x32x16_f16(fa10, fb0, acc1, 0, 0, 0);
        acc1 = __builtin_amdgcn_mfma_f32_32x32x16_f16(fa11, fb1, acc1, 0, 0, 0);
        if (ks < 15) {
            asm volatile("s_waitcnt vmcnt(0)" ::: "memory");   // next buf staged
            __builtin_amdgcn_s_barrier();                      // all waves done reading cur
        }
    }

    // epilogue (mapping validated in R4): D col = t, row = (reg&3)+8*(reg>>2)+4*h
    const int TK = 1 << tkshift;
    const int trow = tt * 64 + wn * 32 + r31;
    const int slice = Bi * 16 + (trow >> tkshift);
    const int t = trow & (TK - 1);
    const int nf0 = mt * 128 + wm * 64 + 4 * h;
#pragma unroll
    for (int ab = 0; ab < 2; ++ab) {
        const f32x16 acc = ab ? acc1 : acc0;
#pragma unroll
        for (int reg = 0; reg < 16; ++reg) {
            const int nf = nf0 + ab * 32 + (reg & 3) + 8 * (reg >> 2);
            Y[((size_t)(slice * 512 + nf) << tkshift) + t] = acc[reg] * C2;
        }
    }
}

// ---------------------------------------------------------------------------
// Fused score + softmax + context.
// score[q][k] = sum_v + sum_n (-2 v_n) * rcp(1 + exp2(pqs+pks))
// ctx[q][n]   = sum_k p[q][k] * keys[k][n]   (raw keys)
// Block: one (slice, q-tile of 4). 512 threads.
// ---------------------------------------------------------------------------
DEV_INLINE float wave_rmax(float v) {
#pragma unroll
    for (int off = 32; off; off >>= 1) v = fmaxf(v, __shfl_xor(v, off, 64));
    return v;
}
DEV_INLINE float wave_rsum(float v) {
#pragma unroll
    for (int off = 32; off; off >>= 1) v += __shfl_xor(v, off, 64);
    return v;
}

__global__ __launch_bounds__(512)
void score_ctx_kernel(const float* __restrict__ pqT,   // [32][512][64]
                      const float* __restrict__ pkT,   // [32][512][128]
                      const float* __restrict__ vatt,  // [512]
                      const float* __restrict__ keys,  // [32][128][512]
                      float* __restrict__ sc_out,      // [32][64][128]
                      float* __restrict__ ctx)         // [32][64][512]
{
    const int slice = blockIdx.x >> 4;
    const int q0    = (blockIdx.x & 15) * 4;
    const int tid   = threadIdx.x;
    const int k     = tid & 127;
    const int nh    = tid >> 7;   // 0..3

    __shared__ __align__(16) float pql[512][4];   // pql[n][j]
    __shared__ float wl[512];                     // -2*v
    __shared__ float partial[3][4][128];
    __shared__ __align__(16) float sc[4][128];
    __shared__ float wredm[8], wreds[8], wsum[8];

    {   // stage pq tile, w = -2*v, block-reduce sum_v
        const float vv = vatt[tid];
        wl[tid] = -2.f * vv;
        const float4 q4 = *reinterpret_cast<const float4*>(
            pqT + ((size_t)slice * 512 + tid) * 64 + q0);
        *reinterpret_cast<float4*>(&pql[tid][0]) = q4;
        const float s = wave_rsum(vv);
        if ((tid & 63) == 0) wsum[tid >> 6] = s;
    }
    __syncthreads();
    float sumv = 0.f;
#pragma unroll
    for (int w = 0; w < 8; ++w) sumv += wsum[w];

    // main score loop: 128 n per thread, 4 q's
    const float* __restrict__ pkp = pkT + ((size_t)slice * 512 + nh * 128) * 128 + k;
    float a0 = 0.f, a1 = 0.f, a2 = 0.f, a3 = 0.f;
#pragma unroll 4
    for (int n = 0; n < 128; ++n) {
        const float pk = pkp[(size_t)n * 128];
        const float4 pq4 = *reinterpret_cast<const float4*>(&pql[nh * 128 + n][0]);
        const float w = wl[nh * 128 + n];
        const float e0 = __builtin_amdgcn_exp2f(pq4.x + pk);
        const float e1 = __builtin_amdgcn_exp2f(pq4.y + pk);
        const float e2 = __builtin_amdgcn_exp2f(pq4.z + pk);
        const float e3 = __builtin_amdgcn_exp2f(pq4.w + pk);
        a0 = fmaf(w, __builtin_amdgcn_rcpf(e0 + 1.f), a0);
        a1 = fmaf(w, __builtin_amdgcn_rcpf(e1 + 1.f), a1);
        a2 = fmaf(w, __builtin_amdgcn_rcpf(e2 + 1.f), a2);
        a3 = fmaf(w, __builtin_amdgcn_rcpf(e3 + 1.f), a3);
    }
    if (nh) {
        partial[nh - 1][0][k] = a0; partial[nh - 1][1][k] = a1;
        partial[nh - 1][2][k] = a2; partial[nh - 1][3][k] = a3;
    }
    __syncthreads();
    if (!nh) {
        sc[0][k] = a0 + partial[0][0][k] + partial[1][0][k] + partial[2][0][k] + sumv;
        sc[1][k] = a1 + partial[0][1][k] + partial[1][1][k] + partial[2][1][k] + sumv;
        sc[2][k] = a2 + partial[0][2][k] + partial[1][2][k] + partial[2][2][k] + sumv;
        sc[3][k] = a3 + partial[0][3][k] + partial[1][3][k] + partial[2][3][k] + sumv;
    }
    __syncthreads();

    // softmax over k=128 per q; group j = nh handles q0+j
    const int j = nh;
    const float orig = sc[j][k];
    float m = wave_rmax(orig);
    if ((tid & 63) == 0) wredm[tid >> 6] = m;
    __syncthreads();
    m = fmaxf(wredm[2 * j], wredm[2 * j + 1]);
    const float e = __builtin_amdgcn_exp2f((orig - m) * LOG2E);
    float s = wave_rsum(e);
    if ((tid & 63) == 0) wreds[tid >> 6] = s;
    __syncthreads();
    s = wreds[2 * j] + wreds[2 * j + 1];
    const float p = e * __builtin_amdgcn_rcpf(s);
    sc_out[((size_t)slice * 64 + q0 + j) * 128 + k] = p;
    sc[j][k] = p;                       // own element, no race
    __syncthreads();

    // context phase: thread (q = tid>>7, n4 = tid&127)
    const int q = nh, n4 = k;
    const float* __restrict__ kb = keys + (size_t)slice * 65536 + n4 * 4;
    float4 acc = {0.f, 0.f, 0.f, 0.f};
#pragma unroll 2
    for (int k4 = 0; k4 < 32; ++k4) {
        const float4 pv = *reinterpret_cast<const float4*>(&sc[q][k4 * 4]);
        const float4 kv0 = *reinterpret_cast<const float4*>(kb + (size_t)(k4 * 4 + 0) * 512);
        const float4 kv1 = *reinterpret_cast<const float4*>(kb + (size_t)(k4 * 4 + 1) * 512);
        const float4 kv2 = *reinterpret_cast<const float4*>(kb + (size_t)(k4 * 4 + 2) * 512);
        const float4 kv3 = *reinterpret_cast<const float4*>(kb + (size_t)(k4 * 4 + 3) * 512);
        acc.x = fmaf(pv.x, kv0.x, acc.x); acc.y = fmaf(pv.x, kv0.y, acc.y);
        acc.z = fmaf(pv.x, kv0.z, acc.z); acc.w = fmaf(pv.x, kv0.w, acc.w);
        acc.x = fmaf(pv.y, kv1.x, acc.x); acc.y = fmaf(pv.y, kv1.y, acc.y);
        acc.z = fmaf(pv.y, kv1.z, acc.z); acc.w = fmaf(pv.y, kv1.w, acc.w);
        acc.x = fmaf(pv.z, kv2.x, acc.x); acc.y = fmaf(pv.z, kv2.y, acc.y);
        acc.z = fmaf(pv.z, kv2.z, acc.z); acc.w = fmaf(pv.z, kv2.w, acc.w);
        acc.x = fmaf(pv.w, kv3.x, acc.x); acc.y = fmaf(pv.w, kv3.y, acc.y);
        acc.z = fmaf(pv.w, kv3.z, acc.z); acc.w = fmaf(pv.w, kv3.w, acc.w);
    }
    *reinterpret_cast<float4*>(ctx + ((size_t)slice * 64 + q0 + q) * 512 + n4 * 4) = acc;
}

// ---------------------------------------------------------------------------
extern "C" void kernel_launch(void* const* d_in, const int* in_sizes, int n_in,
                              void* d_out, int out_size, void* d_ws, size_t ws_size,
                              hipStream_t stream)
{
    const float* query = (const float*)d_in[0];
    const float* keys  = (const float*)d_in[1];
    const float* Wq    = (const float*)d_in[2];
    const float* Wk    = (const float*)d_in[3];
    const float* vatt  = (const float*)d_in[4];

    float* ctx_out = (float*)d_out;
    float* sc_out  = ctx_out + (size_t)32 * 64 * 512;

    float* pqT = (float*)d_ws;                                // 4MB
    float* pkT = pqT + (size_t)32 * 512 * 64;                 // 8MB
    _Float16* X16 = (_Float16*)((char*)d_ws + 12 * 1024 * 1024);  // 8MB f16

    cvt_f16_kernel<<<dim3(4096), 256, 0, stream>>>(query, keys, Wq, Wk, (uint2*)X16);
    proj_mfma_kernel<<<dim3(384), 256, 0, stream>>>(X16, pqT, pkT);
    score_ctx_kernel<<<dim3(512), 512, 0, stream>>>(pqT, pkT, vatt, keys, sc_out, ctx_out);
}

// Round 6
// 63.385 us; speedup vs baseline: 7.7280x; 1.0702x over previous
//
#include <hip/hip_runtime.h>

// Problem dims: B=2, b=16, t_q=64, t_k=128, d=512, slices = 32
// d_out = context [32][64][512] f32 ++ scores_normalized [32][64][128] f32
// d_ws  = pqT [32][512][64] (4MB) ++ pkT [32][512][128] (8MB) ++ X16 (8MB f16)
//   X16 layout (f16 units): query16 @0 | keys16 @1048576 | Wq16 @3145728 | Wk16 @3670016

#define DEV_INLINE __device__ __forceinline__

constexpr float C2    = 2.8853900817779268f;  // 2*log2(e)
constexpr float LOG2E = 1.4426950408889634f;

typedef _Float16 f16x8 __attribute__((ext_vector_type(8)));
typedef float    f32x16 __attribute__((ext_vector_type(16)));

DEV_INLINE unsigned int pk2(float a, float b) {
    auto h = __builtin_amdgcn_cvt_pkrtz(a, b);
    return __builtin_bit_cast(unsigned int, h);
}

#define GL2LDS16(g, l) __builtin_amdgcn_global_load_lds( \
    (const __attribute__((address_space(1))) void*)(g),  \
    (__attribute__((address_space(3))) void*)(l), 16, 0, 0)

// ---------------------------------------------------------------------------
// One-shot f32 -> f16 conversion of all GEMM operands (BW-bound).
// ---------------------------------------------------------------------------
__global__ __launch_bounds__(256)
void cvt_f16_kernel(const float* __restrict__ query, const float* __restrict__ keys,
                    const float* __restrict__ Wq,    const float* __restrict__ Wk,
                    uint2* __restrict__ dst)      // 1,048,576 float4 -> uint2(4 f16)
{
    const int i4 = blockIdx.x * 256 + threadIdx.x;      // 0 .. 1,048,575
    const float* src; int base;
    if (i4 < 262144)      { src = query; base = 0; }
    else if (i4 < 786432) { src = keys;  base = 262144; }
    else if (i4 < 917504) { src = Wq;    base = 786432; }
    else                  { src = Wk;    base = 917504; }
    const float4 v = *reinterpret_cast<const float4*>(src + (size_t)(i4 - base) * 4);
    dst[i4] = make_uint2(pk2(v.x, v.y), pk2(v.z, v.w));
}

// ---------------------------------------------------------------------------
// fp16 MFMA projection GEMM, global_load_lds staging, double-buffered LDS.
// Y[slice][n][t] = C2 * dot(X[t-row], W[n-row]).  A = W (M=n), B = X (N=t).
// Tile 128(M) x 64(N), BK=32, 256 threads (4 waves, 2M x 2N), frags 32x32x16.
// XCD-chunked blockIdx swizzle: 48 consecutive logical blocks per XCD.
// Logical blocks 0..127: query (TK=64). 128..383: keys (TK=128).
// ---------------------------------------------------------------------------
__global__ __launch_bounds__(256)
void proj_mfma_kernel(const _Float16* __restrict__ X16,
                      float* __restrict__ pqT, float* __restrict__ pkT)
{
    __shared__ __align__(16) unsigned char smem[24576];   // 2 x (A 8KB + B 4KB)

    // bijective chunked XCD swizzle (384 % 8 == 0): xcd gets 48 contiguous ids
    const int bid = (blockIdx.x & 7) * 48 + (blockIdx.x >> 3);

    int Bi, mt, tt, tkshift;
    const _Float16 *Wb, *Xb; float* Y;
    if (bid < 128) {      // query GEMM
        Bi = bid >> 6; mt = (bid >> 4) & 3; tt = bid & 15;
        Xb = X16 + ((size_t)Bi * 1024 + tt * 64) * 512;
        Wb = X16 + 3145728 + (size_t)Bi * 262144 + (size_t)(mt * 128) * 512;
        Y = pqT; tkshift = 6;
    } else {              // keys GEMM
        const int b2 = bid - 128;
        Bi = b2 >> 7; mt = (b2 >> 5) & 3; tt = b2 & 31;
        Xb = X16 + 1048576 + ((size_t)Bi * 2048 + tt * 64) * 512;
        Wb = X16 + 3670016 + (size_t)Bi * 262144 + (size_t)(mt * 128) * 512;
        Y = pkT; tkshift = 7;
    }
    const int tid = threadIdx.x;

    // staging: linear LDS u -> global (row = u>>2, actual slot = (u&3) ^ ((row>>1)&3))
    auto srcoff = [](int u) {
        const int row = u >> 2, s = (u & 3) ^ ((row >> 1) & 3);
        return (size_t)row * 512 + s * 8;
    };
    const _Float16* gA0 = Wb + srcoff(tid);         // A rows 0..63
    const _Float16* gA1 = Wb + srcoff(tid + 256);   // A rows 64..127
    const _Float16* gB  = Xb + srcoff(tid);         // B rows 0..63
    unsigned char* const ldsA0 = smem + tid * 16;
    unsigned char* const ldsA1 = smem + 4096 + tid * 16;
    unsigned char* const ldsB  = smem + 8192 + tid * 16;

    // wave decomposition / fragment read offsets (swizzle matches source perm)
    const int wid = tid >> 6, lane = tid & 63;
    const int wm = wid >> 1, wn = wid & 1;
    const int r31 = lane & 31, h = lane >> 5;
    auto lofs = [](int row, int slot) {
        return row * 64 + ((slot ^ ((row >> 1) & 3)) * 16);
    };
    const int rowA0 = wm * 64 + r31, rowA1 = rowA0 + 32, rowB = wn * 32 + r31;
    const int a00 = lofs(rowA0, h),     a01 = lofs(rowA0, 2 + h);
    const int a10 = lofs(rowA1, h),     a11 = lofs(rowA1, 2 + h);
    const int b0  = 8192 + lofs(rowB, h), b1 = 8192 + lofs(rowB, 2 + h);

    f32x16 acc0, acc1;
#pragma unroll
    for (int i = 0; i < 16; ++i) { acc0[i] = 0.f; acc1[i] = 0.f; }

    // prologue: stage K-step 0 into buf0
    GL2LDS16(gA0, ldsA0);
    GL2LDS16(gA1, ldsA1);
    GL2LDS16(gB,  ldsB);
    asm volatile("s_waitcnt vmcnt(0)" ::: "memory");
    __builtin_amdgcn_s_barrier();

    for (int ks = 0; ks < 16; ++ks) {
        const int buf = ks & 1;
        if (ks < 15) {                       // stage next K-step into other buf
            const int ko = (ks + 1) * 32, bo = (buf ^ 1) * 12288;
            GL2LDS16(gA0 + ko, ldsA0 + bo);
            GL2LDS16(gA1 + ko, ldsA1 + bo);
            GL2LDS16(gB  + ko, ldsB  + bo);
        }
        const unsigned char* sb = smem + buf * 12288;
        const f16x8 fa00 = *reinterpret_cast<const f16x8*>(sb + a00);
        const f16x8 fa01 = *reinterpret_cast<const f16x8*>(sb + a01);
        const f16x8 fa10 = *reinterpret_cast<const f16x8*>(sb + a10);
        const f16x8 fa11 = *reinterpret_cast<const f16x8*>(sb + a11);
        const f16x8 fb0  = *reinterpret_cast<const f16x8*>(sb + b0);
        const f16x8 fb1  = *reinterpret_cast<const f16x8*>(sb + b1);
        acc0 = __builtin_amdgcn_mfma_f32_32x32x16_f16(fa00, fb0, acc0, 0, 0, 0);
        acc0 = __builtin_amdgcn_mfma_f32_32x32x16_f16(fa01, fb1, acc0, 0, 0, 0);
        acc1 = __builtin_amdgcn_mfma_f32_32x32x16_f16(fa10, fb0, acc1, 0, 0, 0);
        acc1 = __builtin_amdgcn_mfma_f32_32x32x16_f16(fa11, fb1, acc1, 0, 0, 0);
        if (ks < 15) {
            asm volatile("s_waitcnt vmcnt(0)" ::: "memory");   // next buf staged
            __builtin_amdgcn_s_barrier();                      // all waves done reading cur
        }
    }

    // epilogue (mapping validated in R4): D col = t, row = (reg&3)+8*(reg>>2)+4*h
    const int TK = 1 << tkshift;
    const int trow = tt * 64 + wn * 32 + r31;
    const int slice = Bi * 16 + (trow >> tkshift);
    const int t = trow & (TK - 1);
    const int nf0 = mt * 128 + wm * 64 + 4 * h;
#pragma unroll
    for (int ab = 0; ab < 2; ++ab) {
        const f32x16 acc = ab ? acc1 : acc0;
#pragma unroll
        for (int reg = 0; reg < 16; ++reg) {
            const int nf = nf0 + ab * 32 + (reg & 3) + 8 * (reg >> 2);
            Y[((size_t)(slice * 512 + nf) << tkshift) + t] = acc[reg] * C2;
        }
    }
}

// ---------------------------------------------------------------------------
// Fused score + softmax + context.
// score[q][k] = sum_v + sum_n (-2 v_n) * rcp(1 + exp2(pqs+pks))
// ctx[q][n]   = sum_k p[q][k] * keys[k][n]   (raw keys)
// Block: one (slice, q-tile of 4). 512 threads.
// XCD swizzle: xcd = blockIdx&7 owns 4 slices -> slice panels XCD-local.
// ---------------------------------------------------------------------------
DEV_INLINE float wave_rmax(float v) {
#pragma unroll
    for (int off = 32; off; off >>= 1) v = fmaxf(v, __shfl_xor(v, off, 64));
    return v;
}
DEV_INLINE float wave_rsum(float v) {
#pragma unroll
    for (int off = 32; off; off >>= 1) v += __shfl_xor(v, off, 64);
    return v;
}

__global__ __launch_bounds__(512)
void score_ctx_kernel(const float* __restrict__ pqT,   // [32][512][64]
                      const float* __restrict__ pkT,   // [32][512][128]
                      const float* __restrict__ vatt,  // [512]
                      const float* __restrict__ keys,  // [32][128][512]
                      float* __restrict__ sc_out,      // [32][64][128]
                      float* __restrict__ ctx)         // [32][64][512]
{
    // bijective XCD swizzle (512 blocks, 8 XCDs, 64 per XCD = 4 slices x 16 q-tiles)
    const int xcd = blockIdx.x & 7, ix = blockIdx.x >> 3;
    const int slice = xcd * 4 + (ix >> 4);
    const int q0    = (ix & 15) * 4;
    const int tid   = threadIdx.x;
    const int k     = tid & 127;
    const int nh    = tid >> 7;   // 0..3

    __shared__ __align__(16) float pql[512][4];   // pql[n][j]
    __shared__ float wl[512];                     // -2*v
    __shared__ float partial[3][4][128];
    __shared__ __align__(16) float sc[4][128];
    __shared__ float wredm[8], wreds[8], wsum[8];

    {   // stage pq tile, w = -2*v, block-reduce sum_v
        const float vv = vatt[tid];
        wl[tid] = -2.f * vv;
        const float4 q4 = *reinterpret_cast<const float4*>(
            pqT + ((size_t)slice * 512 + tid) * 64 + q0);
        *reinterpret_cast<float4*>(&pql[tid][0]) = q4;
        const float s = wave_rsum(vv);
        if ((tid & 63) == 0) wsum[tid >> 6] = s;
    }
    __syncthreads();
    float sumv = 0.f;
#pragma unroll
    for (int w = 0; w < 8; ++w) sumv += wsum[w];

    // main score loop: 128 n per thread, 4 q's
    const float* __restrict__ pkp = pkT + ((size_t)slice * 512 + nh * 128) * 128 + k;
    float a0 = 0.f, a1 = 0.f, a2 = 0.f, a3 = 0.f;
#pragma unroll 4
    for (int n = 0; n < 128; ++n) {
        const float pk = pkp[(size_t)n * 128];
        const float4 pq4 = *reinterpret_cast<const float4*>(&pql[nh * 128 + n][0]);
        const float w = wl[nh * 128 + n];
        const float e0 = __builtin_amdgcn_exp2f(pq4.x + pk);
        const float e1 = __builtin_amdgcn_exp2f(pq4.y + pk);
        const float e2 = __builtin_amdgcn_exp2f(pq4.z + pk);
        const float e3 = __builtin_amdgcn_exp2f(pq4.w + pk);
        a0 = fmaf(w, __builtin_amdgcn_rcpf(e0 + 1.f), a0);
        a1 = fmaf(w, __builtin_amdgcn_rcpf(e1 + 1.f), a1);
        a2 = fmaf(w, __builtin_amdgcn_rcpf(e2 + 1.f), a2);
        a3 = fmaf(w, __builtin_amdgcn_rcpf(e3 + 1.f), a3);
    }
    if (nh) {
        partial[nh - 1][0][k] = a0; partial[nh - 1][1][k] = a1;
        partial[nh - 1][2][k] = a2; partial[nh - 1][3][k] = a3;
    }
    __syncthreads();
    if (!nh) {
        sc[0][k] = a0 + partial[0][0][k] + partial[1][0][k] + partial[2][0][k] + sumv;
        sc[1][k] = a1 + partial[0][1][k] + partial[1][1][k] + partial[2][1][k] + sumv;
        sc[2][k] = a2 + partial[0][2][k] + partial[1][2][k] + partial[2][2][k] + sumv;
        sc[3][k] = a3 + partial[0][3][k] + partial[1][3][k] + partial[2][3][k] + sumv;
    }
    __syncthreads();

    // softmax over k=128 per q; group j = nh handles q0+j
    const int j = nh;
    const float orig = sc[j][k];
    float m = wave_rmax(orig);
    if ((tid & 63) == 0) wredm[tid >> 6] = m;
    __syncthreads();
    m = fmaxf(wredm[2 * j], wredm[2 * j + 1]);
    const float e = __builtin_amdgcn_exp2f((orig - m) * LOG2E);
    float s = wave_rsum(e);
    if ((tid & 63) == 0) wreds[tid >> 6] = s;
    __syncthreads();
    s = wreds[2 * j] + wreds[2 * j + 1];
    const float p = e * __builtin_amdgcn_rcpf(s);
    sc_out[((size_t)slice * 64 + q0 + j) * 128 + k] = p;
    sc[j][k] = p;                       // own element, no race
    __syncthreads();

    // context phase: thread (q = tid>>7, n4 = tid&127)
    const int q = nh, n4 = k;
    const float* __restrict__ kb = keys + (size_t)slice * 65536 + n4 * 4;
    float4 acc = {0.f, 0.f, 0.f, 0.f};
#pragma unroll 2
    for (int k4 = 0; k4 < 32; ++k4) {
        const float4 pv = *reinterpret_cast<const float4*>(&sc[q][k4 * 4]);
        const float4 kv0 = *reinterpret_cast<const float4*>(kb + (size_t)(k4 * 4 + 0) * 512);
        const float4 kv1 = *reinterpret_cast<const float4*>(kb + (size_t)(k4 * 4 + 1) * 512);
        const float4 kv2 = *reinterpret_cast<const float4*>(kb + (size_t)(k4 * 4 + 2) * 512);
        const float4 kv3 = *reinterpret_cast<const float4*>(kb + (size_t)(k4 * 4 + 3) * 512);
        acc.x = fmaf(pv.x, kv0.x, acc.x); acc.y = fmaf(pv.x, kv0.y, acc.y);
        acc.z = fmaf(pv.x, kv0.z, acc.z); acc.w = fmaf(pv.x, kv0.w, acc.w);
        acc.x = fmaf(pv.y, kv1.x, acc.x); acc.y = fmaf(pv.y, kv1.y, acc.y);
        acc.z = fmaf(pv.y, kv1.z, acc.z); acc.w = fmaf(pv.y, kv1.w, acc.w);
        acc.x = fmaf(pv.z, kv2.x, acc.x); acc.y = fmaf(pv.z, kv2.y, acc.y);
        acc.z = fmaf(pv.z, kv2.z, acc.z); acc.w = fmaf(pv.z, kv2.w, acc.w);
        acc.x = fmaf(pv.w, kv3.x, acc.x); acc.y = fmaf(pv.w, kv3.y, acc.y);
        acc.z = fmaf(pv.w, kv3.z, acc.z); acc.w = fmaf(pv.w, kv3.w, acc.w);
    }
    *reinterpret_cast<float4*>(ctx + ((size_t)slice * 64 + q0 + q) * 512 + n4 * 4) = acc;
}

// ---------------------------------------------------------------------------
extern "C" void kernel_launch(void* const* d_in, const int* in_sizes, int n_in,
                              void* d_out, int out_size, void* d_ws, size_t ws_size,
                              hipStream_t stream)
{
    const float* query = (const float*)d_in[0];
    const float* keys  = (const float*)d_in[1];
    const float* Wq    = (const float*)d_in[2];
    const float* Wk    = (const float*)d_in[3];
    const float* vatt  = (const float*)d_in[4];

    float* ctx_out = (float*)d_out;
    float* sc_out  = ctx_out + (size_t)32 * 64 * 512;

    float* pqT = (float*)d_ws;                                // 4MB
    float* pkT = pqT + (size_t)32 * 512 * 64;                 // 8MB
    _Float16* X16 = (_Float16*)((char*)d_ws + 12 * 1024 * 1024);  // 8MB f16

    cvt_f16_kernel<<<dim3(4096), 256, 0, stream>>>(query, keys, Wq, Wk, (uint2*)X16);
    proj_mfma_kernel<<<dim3(384), 256, 0, stream>>>(X16, pqT, pkT);
    score_ctx_kernel<<<dim3(512), 512, 0, stream>>>(pqT, pkT, vatt, keys, sc_out, ctx_out);
}